// Round 21
// baseline (131.724 us; speedup 1.0000x reference)
//
#include <hip/hip_runtime.h>
#include <hip/hip_bf16.h>
#include <stdint.h>

typedef __attribute__((ext_vector_type(8))) __bf16 bf16x8;
typedef __attribute__((ext_vector_type(4))) float f32x4;
typedef __hip_bfloat16 bf16;

#define GLDS(g, l) __builtin_amdgcn_global_load_lds( \
    (const __attribute__((address_space(1))) void*)(g), \
    (__attribute__((address_space(3))) void*)(l), 16, 0, 0)

#define SCALE_Q 0.18033688f   // 0.125 * log2(e): softmax runs in exp2 domain
#define MFIX 12.0f            // fixed softmax max (log2 domain)

// ---------------- workspace layout (bytes) ----------------
#define OFF_XB     ((size_t)0          )
#define OFF_WQKVB  ((size_t)8388608    )
#define OFF_WOB    ((size_t)14680064   )
#define OFF_QB     ((size_t)16777216   )
#define OFF_KB     ((size_t)25165824   )
#define OFF_VTB    ((size_t)33554432   )
#define OFF_CS     ((size_t)41943040   )
#define OFF_SN     ((size_t)42205184   )

// ---------------- fp32 -> bf16 conversion + RoPE table (region 5) ----------------
__global__ void prep_kernel(const float* __restrict__ x, const float* __restrict__ wq,
                            const float* __restrict__ wk, const float* __restrict__ wv,
                            const float* __restrict__ wo,
                            bf16* __restrict__ xb, bf16* __restrict__ wqkvb,
                            bf16* __restrict__ wob,
                            const int* __restrict__ pos, const void* __restrict__ theta_p,
                            float* __restrict__ cst, float* __restrict__ snt)
{
    const int region = blockIdx.y;
    if (region == 5) {                      // RoPE cos/sin table: [s][i], i = d/2
        if (blockIdx.x >= 256) return;
        const int t = blockIdx.x * 256 + threadIdx.x;   // 2048*32 = 65536
        const int s = t >> 5, i = t & 31;
        const int ti = ((const int*)theta_p)[0];
        const float theta = (ti > 0 && ti < 100000000) ? (float)ti : ((const float*)theta_p)[0];
        const float fr = expf(-(float)i * (1.0f / 32.0f) * logf(theta));
        const float ang = (float)pos[s] * fr;
        cst[t] = cosf(ang);
        snt[t] = sinf(ang);
        return;
    }
    const float* src;
    bf16* dst;
    int count;
    switch (region) {
        case 0:  src = x;  dst = xb;              count = 4096 * 1024; break;
        case 1:  src = wq; dst = wqkvb;           count = 1024 * 1024; break;
        case 2:  src = wk; dst = wqkvb + 1048576; count = 1024 * 1024; break;
        case 3:  src = wv; dst = wqkvb + 2097152; count = 1024 * 1024; break;
        default: src = wo; dst = wob;             count = 1024 * 1024; break;
    }
    const int i = (blockIdx.x * 256 + threadIdx.x) * 4;
    if (i >= count) return;
    const float4 v = *(const float4*)(src + i);
    union { bf16 h[4]; short4 s4; } u;
    u.h[0] = __float2bfloat16(v.x);
    u.h[1] = __float2bfloat16(v.y);
    u.h[2] = __float2bfloat16(v.z);
    u.h[3] = __float2bfloat16(v.w);
    *(short4*)(dst + i) = u.s4;
}

// ---------------- QKV GEMM: 512 threads / 8 waves (2x4), 128x128, BK=64 ----------------
// Double-buffered LDS (64 KB), counted-vmcnt prefetch: 4 GLDS/stage (A 2 +
// B 2, each 64 rows x 128B at 512thr x 16B), steady vmcnt(4). 16 steps,
// 16 MFMA/wave/step (R20-proven phase density). 128B rows swizzled
// (seg ^ (row&7))*16 on both global source and ds_read.
// Epilogue: RoPE scatter for Q/K; V transposed via LDS (stride 136).
__global__ __launch_bounds__(512) void gemm_qkv512(
    const bf16* __restrict__ A, const bf16* __restrict__ B,
    bf16* __restrict__ qb, bf16* __restrict__ kb, bf16* __restrict__ vtb,
    const float* __restrict__ cst, const float* __restrict__ snt)
{
    constexpr int K = 1024;
    constexpr int TBYTES = 128 * 128;        // one 128-row x 128B buffer (16 KB)
    constexpr int POOL = 4 * TBYTES;         // A0 A1 B0 B1 = 64 KB (> 34.8 KB Tl)
    __shared__ __align__(16) char smem[POOL];
    const int tid = threadIdx.x;
    const int wave = tid >> 6, lane = tid & 63;
    const int lr = lane & 15, lk = lane >> 4;

    // bijective XCD swizzle (nwg = 768, %8 == 0)
    const int nwg = gridDim.x * gridDim.y;
    const int flat = blockIdx.y * gridDim.x + blockIdx.x;
    const int wg = (flat & 7) * (nwg >> 3) + (flat >> 3);
    const int m0 = (wg % gridDim.x) * 128;
    const int n0 = (wg / gridDim.x) * 128;

    const int wm = (wave >> 2) * 64;
    const int wn = (wave & 3) * 32;
    const int srow = tid >> 3, sseg = tid & 7;                 // 64 rows x 8 segs / GLDS
    const int swel = (sseg ^ (srow & 7)) * 8;                  // pre-swizzled elems

    f32x4 acc[4][2] = {};

    const bf16* aRow = A + (size_t)(m0 + srow) * K + swel;
    const bf16* bRow = B + (size_t)(n0 + srow) * K + swel;
    const size_t rowK64 = (size_t)64 * K;

    auto STAGE = [&](int step, int c) {
        char* lA = smem + c * TBYTES + tid * 16;
        char* lB = smem + 2 * TBYTES + c * TBYTES + tid * 16;
        const int off = step * 64;
#pragma unroll
        for (int g = 0; g < 2; ++g) {
            GLDS(aRow + off + (size_t)g * rowK64, lA + g * 8192);
            GLDS(bRow + off + (size_t)g * rowK64, lB + g * 8192);
        }
    };

    constexpr int NSTEP = K / 64;

    STAGE(0, 0);

    for (int ks = 0; ks < NSTEP; ++ks) {
        const int c = ks & 1;
        if (ks < NSTEP - 1) {
            STAGE(ks + 1, c ^ 1);
            asm volatile("s_waitcnt vmcnt(4)" ::: "memory");
        } else {
            asm volatile("s_waitcnt vmcnt(0)" ::: "memory");
        }
        __builtin_amdgcn_s_barrier();
        __builtin_amdgcn_sched_barrier(0);
        const char* aBase = smem + c * TBYTES;
        const char* bBase = smem + 2 * TBYTES + c * TBYTES;

#pragma unroll
        for (int kk = 0; kk < 2; ++kk) {
            const int seg = kk * 4 + lk;          // 16B segment 0..7
            bf16x8 af[4], bfr[2];
#pragma unroll
            for (int i = 0; i < 4; ++i) {
                const int R = wm + i * 16 + lr;
                af[i] = *(const bf16x8*)(aBase + R * 128 + ((seg ^ (R & 7)) << 4));
            }
#pragma unroll
            for (int j = 0; j < 2; ++j) {
                const int R = wn + j * 16 + lr;
                bfr[j] = *(const bf16x8*)(bBase + R * 128 + ((seg ^ (R & 7)) << 4));
            }
#pragma unroll
            for (int i = 0; i < 4; ++i)
#pragma unroll
                for (int j = 0; j < 2; ++j)
                    acc[i][j] = __builtin_amdgcn_mfma_f32_16x16x32_bf16(af[i], bfr[j], acc[i][j], 0, 0, 0);
        }
        __builtin_amdgcn_sched_barrier(0);
        __builtin_amdgcn_s_barrier();
    }

    const int matn = n0 >> 10;   // 0=Q 1=K 2=V, uniform per block
    if (matn == 2) {
        // V: transpose 128x128 tile via LDS (stride 136), coalesced stores.
        bf16* Tl = (bf16*)smem;
        __syncthreads();
#pragma unroll
        for (int i = 0; i < 4; ++i)
#pragma unroll
            for (int j = 0; j < 2; ++j)
#pragma unroll
                for (int r = 0; r < 4; ++r) {
                    const int trow = wm + i * 16 + lk * 4 + r;   // s-local
                    const int tcol = wn + j * 16 + lr;           // col-local
                    Tl[tcol * 136 + trow] = __float2bfloat16(acc[i][j][r]);
                }
        __syncthreads();
        const int b = m0 >> 11;
        const int s0 = m0 & 2047;
#pragma unroll
        for (int k = 0; k < 4; ++k) {
            const int cc = wave * 16 + k * 4 + lk;               // tile col
            const int e = (n0 + cc) & 1023;
            const size_t bhi = (size_t)(b * 16 + (e >> 6));
            bf16* dst = vtb + (bhi * 64 + (e & 63)) * 2048 + s0 + lr * 8;
            *(uint4*)dst = *(const uint4*)&Tl[cc * 136 + lr * 8];
        }
    } else {
#pragma unroll
        for (int i = 0; i < 4; ++i)
#pragma unroll
            for (int j = 0; j < 2; ++j)
#pragma unroll
                for (int r = 0; r < 4; ++r) {
                    const int row = m0 + wm + i * 16 + lk * 4 + r;
                    const int col = n0 + wn + j * 16 + lr;
                    float v = acc[i][j][r];
                    float p = __shfl_xor(v, 1);        // RoPE pair partner
                    const int e = col & 1023;
                    const int h = e >> 6;
                    const int dd = e & 63;
                    const int b = row >> 11;
                    const int s = row & 2047;
                    const size_t bhi = (size_t)(b * 16 + h);
                    const float cs = cst[s * 32 + (dd >> 1)];
                    const float sn = snt[s * 32 + (dd >> 1)];
                    const float rv = (dd & 1) ? (p * sn + v * cs) : (v * cs - p * sn);
                    if (matn == 0)
                        qb[(bhi * 2048 + s) * 64 + dd] = __float2bfloat16(rv * SCALE_Q);
                    else
                        kb[(bhi * 2048 + s) * 64 + dd] = __float2bfloat16(rv);
                }
    }
}

// ---------------- output GEMM: 64x128 tile, BK=64 (R20 proven) ----------------
__global__ __launch_bounds__(256) void gemm_out64(
    const bf16* __restrict__ A, const bf16* __restrict__ B,
    float* __restrict__ outf)
{
    constexpr int K = 1024, N = 1024;
    constexpr int ABYTES = 64 * 128;         // 8 KB
    constexpr int BBYTES = 128 * 128;        // 16 KB
    __shared__ __align__(16) char smem[2 * (ABYTES + BBYTES)];   // 48 KB
    const int tid = threadIdx.x;
    const int wave = tid >> 6, lane = tid & 63;
    const int lr = lane & 15, lk = lane >> 4;

    // bijective XCD swizzle (nwg = 512, %8 == 0)
    const int nwg = gridDim.x * gridDim.y;
    const int flat = blockIdx.y * gridDim.x + blockIdx.x;
    const int wg = (flat & 7) * (nwg >> 3) + (flat >> 3);
    const int m0 = (wg % gridDim.x) * 64;
    const int n0 = (wg / gridDim.x) * 128;

    const int wm = (wave >> 1) * 32;
    const int wn = (wave & 1) * 64;
    const int srow = tid >> 3, sseg = tid & 7;                 // 32 rows x 8 segs / GLDS
    const int swel = (sseg ^ (srow & 7)) * 8;                  // pre-swizzled elems

    f32x4 acc[2][4] = {};

    const bf16* aRow = A + (size_t)(m0 + srow) * K + swel;
    const bf16* bRow = B + (size_t)(n0 + srow) * K + swel;
    const size_t rowK32 = (size_t)32 * K;

    auto STAGE = [&](int step, int c) {
        char* lA = smem + c * ABYTES + tid * 16;
        char* lB = smem + 2 * ABYTES + c * BBYTES + tid * 16;
        const int off = step * 64;
#pragma unroll
        for (int g = 0; g < 2; ++g)
            GLDS(aRow + off + (size_t)g * rowK32, lA + g * 4096);
#pragma unroll
        for (int g = 0; g < 4; ++g)
            GLDS(bRow + off + (size_t)g * rowK32, lB + g * 4096);
    };

    constexpr int NSTEP = K / 64;

    STAGE(0, 0);

    for (int ks = 0; ks < NSTEP; ++ks) {
        const int c = ks & 1;
        if (ks < NSTEP - 1) {
            STAGE(ks + 1, c ^ 1);
            asm volatile("s_waitcnt vmcnt(6)" ::: "memory");
        } else {
            asm volatile("s_waitcnt vmcnt(0)" ::: "memory");
        }
        __builtin_amdgcn_s_barrier();
        __builtin_amdgcn_sched_barrier(0);
        const char* aBase = smem + c * ABYTES;
        const char* bBase = smem + 2 * ABYTES + c * BBYTES;

#pragma unroll
        for (int kk = 0; kk < 2; ++kk) {
            const int seg = kk * 4 + lk;          // 16B segment 0..7
            bf16x8 af[2], bfr[4];
#pragma unroll
            for (int i = 0; i < 2; ++i) {
                const int R = wm + i * 16 + lr;
                af[i] = *(const bf16x8*)(aBase + R * 128 + ((seg ^ (R & 7)) << 4));
            }
#pragma unroll
            for (int j = 0; j < 4; ++j) {
                const int R = wn + j * 16 + lr;
                bfr[j] = *(const bf16x8*)(bBase + R * 128 + ((seg ^ (R & 7)) << 4));
            }
#pragma unroll
            for (int i = 0; i < 2; ++i)
#pragma unroll
                for (int j = 0; j < 4; ++j)
                    acc[i][j] = __builtin_amdgcn_mfma_f32_16x16x32_bf16(af[i], bfr[j], acc[i][j], 0, 0, 0);
        }
        __builtin_amdgcn_sched_barrier(0);
        __builtin_amdgcn_s_barrier();
    }

#pragma unroll
    for (int i = 0; i < 2; ++i)
#pragma unroll
        for (int j = 0; j < 4; ++j)
#pragma unroll
            for (int r = 0; r < 4; ++r) {
                const int row = m0 + wm + i * 16 + lk * 4 + r;
                const int col = n0 + wn + j * 16 + lr;
                outf[(size_t)row * N + col] = acc[i][j][r];
            }
}

// ---------------- causal flash attention (R12/R14 structure, proven 60.7us) ----------------
__global__ __launch_bounds__(256) void attn_kernel(
    const bf16* __restrict__ qb, const bf16* __restrict__ kb,
    const bf16* __restrict__ vtb, bf16* __restrict__ attnb)
{
    __shared__ __align__(16) bf16 Kl[2][64 * 64];
    __shared__ __align__(16) bf16 Vl[2][64 * 64];
    __shared__ __align__(16) bf16 Pl[4][2][16][72];   // [wave][strip][q][k], 144B rows
    const int tid = threadIdx.x;
    const int wave = tid >> 6, lane = tid & 63;
    const int lr = lane & 15, lk = lane >> 4;
    const int tA = blockIdx.x;            // 0..15  (short strip)
    const int tB = 31 - tA;               // 16..31 (long strip)
    const int bh = blockIdx.y;
    const int qA = tA * 64 + wave * 16;
    const int qB = tB * 64 + wave * 16;

    const bf16* Qp = qb + (size_t)bh * 2048 * 64;
    const bf16* Kp = kb + (size_t)bh * 2048 * 64;
    const bf16* Vp = vtb + (size_t)bh * 64 * 2048;

    const int srow = tid >> 3;
    const int sseg = tid & 7;
    const int sw16 = (sseg ^ (srow & 7)) * 16;
    const char* kg = (const char*)Kp + (size_t)srow * 128 + sw16;
    const char* vg = (const char*)Vp + (size_t)srow * 4096 + sw16;

#define STAGE(kt_, c_) do {                                              \
        const char* kgt = kg + (size_t)(kt_) * 8192;                     \
        GLDS(kgt,              &Kl[c_][0] + tid * 8);                    \
        GLDS(kgt + 32 * 128,   &Kl[c_][0] + 2048 + tid * 8);             \
        const char* vgt = vg + (size_t)(kt_) * 128;                      \
        GLDS(vgt,              &Vl[c_][0] + tid * 8);                    \
        GLDS(vgt + 32 * 4096,  &Vl[c_][0] + 2048 + tid * 8);             \
    } while (0)

    bf16x8 qfA[2], qfB[2];
#pragma unroll
    for (int ks = 0; ks < 2; ++ks) {
        qfA[ks] = *(const bf16x8*)(Qp + (qA + lr) * 64 + ks * 32 + lk * 8);
        qfB[ks] = *(const bf16x8*)(Qp + (qB + lr) * 64 + ks * 32 + lk * 8);
    }

    float sA = 0.f, sB = 0.f;
    f32x4 oA[4] = {}, oB[4] = {};

    STAGE(0, 0);

    const int xoff = (lr & 7) * 8;   // K/V swizzle: row&7 == lr&7 for rows j*16+lr

    for (int kt = 0; kt <= tB; ++kt) {
        const int c = kt & 1;
        const int kv0 = kt * 64;
        const bool doA = (kt <= tA);
        if (kt < tB) {
            STAGE(kt + 1, c ^ 1);
            asm volatile("s_waitcnt vmcnt(4)" ::: "memory");  // kt landed; kt+1 in flight
        } else {
            asm volatile("s_waitcnt vmcnt(0)" ::: "memory");
        }
        __builtin_amdgcn_s_barrier();
        __builtin_amdgcn_sched_barrier(0);
        const bf16* Kc = &Kl[c][0];
        const bf16* Vc = &Vl[c][0];

        // ---- QK^T (swapped): scX[j][r] = P^T[k = j*16+lk*4+r][q = lr] ----
        f32x4 scB[4] = {}, scA[4] = {};
#pragma unroll
        for (int ks = 0; ks < 2; ++ks) {
            bf16x8 kf[4];
#pragma unroll
            for (int j = 0; j < 4; ++j)
                kf[j] = *(const bf16x8*)(Kc + (j * 16 + lr) * 64 + ((ks * 32 + lk * 8) ^ xoff));
            __builtin_amdgcn_s_setprio(1);
#pragma unroll
            for (int j = 0; j < 4; ++j)
                scB[j] = __builtin_amdgcn_mfma_f32_16x16x32_bf16(kf[j], qfB[ks], scB[j], 0, 0, 0);
            if (doA) {
#pragma unroll
                for (int j = 0; j < 4; ++j)
                    scA[j] = __builtin_amdgcn_mfma_f32_16x16x32_bf16(kf[j], qfA[ks], scA[j], 0, 0, 0);
            }
            __builtin_amdgcn_s_setprio(0);
        }

        // vf hoisted once per visit; loads overlap the softmax below
        bf16x8 vf[2][4];
#pragma unroll
        for (int ks = 0; ks < 2; ++ks)
#pragma unroll
            for (int j = 0; j < 4; ++j)
                vf[ks][j] = *(const bf16x8*)(Vc + (j * 16 + lr) * 64 + ((ks * 32 + lk * 8) ^ xoff));

        // ---- fixed-max softmax: P = exp2(sc - MFIX); branchless, lane-local ----
        auto smx = [&](f32x4* sc, float& ssum, int qX, bool diag, int st) {
            if (diag) {
#pragma unroll
                for (int j = 0; j < 4; ++j)
#pragma unroll
                    for (int r = 0; r < 4; ++r)
                        if (kv0 + j * 16 + lk * 4 + r > qX + lr) sc[j][r] = -1e30f;
            }
            float l0 = 0.f, l1 = 0.f, l2 = 0.f, l3 = 0.f;
#pragma unroll
            for (int j = 0; j < 4; ++j) {
                float pv[4];
                pv[0] = exp2f(sc[j][0] - MFIX);
                pv[1] = exp2f(sc[j][1] - MFIX);
                pv[2] = exp2f(sc[j][2] - MFIX);
                pv[3] = exp2f(sc[j][3] - MFIX);
                l0 += pv[0]; l1 += pv[1]; l2 += pv[2]; l3 += pv[3];
                union { bf16 h[4]; ushort4 s4; } u;
#pragma unroll
                for (int r = 0; r < 4; ++r) u.h[r] = __float2bfloat16(pv[r]);
                *(ushort4*)(&Pl[wave][st][lr][j * 16 + lk * 4]) = u.s4;
            }
            ssum += (l0 + l1) + (l2 + l3);
        };
        // ---- PV for strip st: o[j] (= O^T[d][q]) += mfma(vf, pf) ----
        auto pv = [&](f32x4* o, int st) {
#pragma unroll
            for (int ks = 0; ks < 2; ++ks) {
                const bf16x8 pf = *(const bf16x8*)(&Pl[wave][st][lr][ks * 32 + lk * 8]);
                __builtin_amdgcn_s_setprio(1);
#pragma unroll
                for (int j = 0; j < 4; ++j)
                    o[j] = __builtin_amdgcn_mfma_f32_16x16x32_bf16(vf[ks][j], pf, o[j], 0, 0, 0);
                __builtin_amdgcn_s_setprio(0);
            }
        };

        smx(scB, sB, qB, kt == tB, 1);
        if (doA) smx(scA, sA, qA, kt == tA, 0);
        pv(oB, 1);
        if (doA) pv(oA, 0);

        __builtin_amdgcn_sched_barrier(0);
        __builtin_amdgcn_s_barrier();   // all reads of buf c done before next stage overwrites
    }

    const int b = bh >> 4, h = bh & 15;
    auto epi = [&](float ssum, f32x4* o, int qX) {
        float s = ssum;
        s += __shfl_xor(s, 16);
        s += __shfl_xor(s, 32);
        const float inv = 1.0f / s;
        const int qq = qX + lr;
        bf16* dst = attnb + (size_t)(b * 2048 + qq) * 1024 + h * 64 + lk * 4;
#pragma unroll
        for (int j = 0; j < 4; ++j) {
            union { bf16 h4[4]; ushort4 s4; } u;
#pragma unroll
            for (int r = 0; r < 4; ++r) u.h4[r] = __float2bfloat16(o[j][r] * inv);
            *(ushort4*)(dst + j * 16) = u.s4;
        }
    };
    epi(sA, oA, qA);
    epi(sB, oB, qB);
#undef STAGE
}

// ---------------- launch ----------------
extern "C" void kernel_launch(void* const* d_in, const int* in_sizes, int n_in,
                              void* d_out, int out_size, void* d_ws, size_t ws_size,
                              hipStream_t stream)
{
    const float* x   = (const float*)d_in[0];
    const float* wq  = (const float*)d_in[1];
    const float* wk  = (const float*)d_in[2];
    const float* wv  = (const float*)d_in[3];
    const float* wo  = (const float*)d_in[4];
    const int*   pos = (const int*)d_in[5];
    const void* theta = d_in[6];

    char* ws = (char*)d_ws;
    bf16* xb    = (bf16*)(ws + OFF_XB);
    bf16* attnb = (bf16*)(ws + OFF_XB);    // reuse: xb consumed before attn writes
    bf16* wqkvb = (bf16*)(ws + OFF_WQKVB);
    bf16* wob   = (bf16*)(ws + OFF_WOB);
    bf16* qb    = (bf16*)(ws + OFF_QB);
    bf16* kb    = (bf16*)(ws + OFF_KB);
    bf16* vtb   = (bf16*)(ws + OFF_VTB);
    float* cst  = (float*)(ws + OFF_CS);
    float* snt  = (float*)(ws + OFF_SN);

    prep_kernel<<<dim3(4096, 6), 256, 0, stream>>>(x, wq, wk, wv, wo, xb, wqkvb, wob,
                                                   pos, theta, cst, snt);
    gemm_qkv512<<<dim3(32, 24), 512, 0, stream>>>(xb, wqkvb, qb, kb, vtb, cst, snt);
    attn_kernel<<<dim3(16, 32), 256, 0, stream>>>(qb, kb, vtb, attnb);
    gemm_out64<<<dim3(64, 8), 256, 0, stream>>>(attnb, wob, (float*)d_out);
}

// Round 22
// 123.902 us; speedup vs baseline: 1.0631x; 1.0631x over previous
//
#include <hip/hip_runtime.h>
#include <hip/hip_bf16.h>
#include <stdint.h>

typedef __attribute__((ext_vector_type(8))) __bf16 bf16x8;
typedef __attribute__((ext_vector_type(4))) float f32x4;
typedef __hip_bfloat16 bf16;

#define GLDS(g, l) __builtin_amdgcn_global_load_lds( \
    (const __attribute__((address_space(1))) void*)(g), \
    (__attribute__((address_space(3))) void*)(l), 16, 0, 0)

#define SCALE_Q 0.18033688f   // 0.125 * log2(e): softmax runs in exp2 domain
#define MFIX 12.0f            // fixed softmax max (log2 domain)

// ---------------- workspace layout (bytes) ----------------
#define OFF_XB     ((size_t)0          )
#define OFF_WQKVB  ((size_t)8388608    )
#define OFF_WOB    ((size_t)14680064   )
#define OFF_QB     ((size_t)16777216   )
#define OFF_KB     ((size_t)25165824   )
#define OFF_VTB    ((size_t)33554432   )
#define OFF_CS     ((size_t)41943040   )
#define OFF_SN     ((size_t)42205184   )

// ---------------- flat prep: fp32->bf16 conversion + RoPE table ----------------
// Blocks 0..8191: 8.39M elements, 4/thread (x -> xb; wq/wk/wv -> wqkvb; wo -> wob).
// Blocks 8192..8447: RoPE cos/sin table (2048 x 32).
__global__ void prep_kernel(const float* __restrict__ x, const float* __restrict__ wq,
                            const float* __restrict__ wk, const float* __restrict__ wv,
                            const float* __restrict__ wo,
                            bf16* __restrict__ xb, bf16* __restrict__ wqkvb,
                            bf16* __restrict__ wob,
                            const int* __restrict__ pos, const void* __restrict__ theta_p,
                            float* __restrict__ cst, float* __restrict__ snt)
{
    const int bid = blockIdx.x;
    if (bid >= 8192) {                      // RoPE table
        const int t = (bid - 8192) * 256 + threadIdx.x;   // 65536
        const int s = t >> 5, i = t & 31;
        const int ti = ((const int*)theta_p)[0];
        const float theta = (ti > 0 && ti < 100000000) ? (float)ti : ((const float*)theta_p)[0];
        const float fr = expf(-(float)i * (1.0f / 32.0f) * logf(theta));
        const float ang = (float)pos[s] * fr;
        cst[t] = cosf(ang);
        snt[t] = sinf(ang);
        return;
    }
    const int i = (bid * 256 + threadIdx.x) * 4;          // [0, 8388608)
    const float* src;
    bf16* dst;
    if (i < 4194304) {                      // x
        src = x + i; dst = xb + i;
    } else {
        const int j = i - 4194304;
        if (j < 3145728) {                  // wq|wk|wv -> contiguous wqkvb
            src = (j < 1048576 ? wq + j : (j < 2097152 ? wk + (j - 1048576)
                                                       : wv + (j - 2097152)));
            dst = wqkvb + j;
        } else {                            // wo
            src = wo + (j - 3145728);
            dst = wob + (j - 3145728);
        }
    }
    const float4 v = *(const float4*)src;
    union { bf16 h[4]; short4 s4; } u;
    u.h[0] = __float2bfloat16(v.x);
    u.h[1] = __float2bfloat16(v.y);
    u.h[2] = __float2bfloat16(v.z);
    u.h[3] = __float2bfloat16(v.w);
    *(short4*)dst = u.s4;
}

// ---------------- QKV GEMM: 512 threads / 8 waves (2x4), 128x128, BK=32 ----------------
// (R18/R20 proven form: 24 waves/CU, dbuf, counted vmcnt(2).)
__global__ __launch_bounds__(512) void gemm_qkv512(
    const bf16* __restrict__ A, const bf16* __restrict__ B,
    bf16* __restrict__ qb, bf16* __restrict__ kb, bf16* __restrict__ vtb,
    const float* __restrict__ cst, const float* __restrict__ snt)
{
    constexpr int K = 1024;
    constexpr int ABYTES = 128 * 64;
    constexpr int POOL = 128 * 136 * 2;     // 34816 > 4*8192
    __shared__ __align__(16) char smem[POOL];
    const int tid = threadIdx.x;
    const int wave = tid >> 6, lane = tid & 63;
    const int lr = lane & 15, lk = lane >> 4;

    // bijective XCD swizzle (nwg = 768, %8 == 0)
    const int nwg = gridDim.x * gridDim.y;
    const int flat = blockIdx.y * gridDim.x + blockIdx.x;
    const int wg = (flat & 7) * (nwg >> 3) + (flat >> 3);
    const int m0 = (wg % gridDim.x) * 128;
    const int n0 = (wg / gridDim.x) * 128;

    const int wm = (wave >> 2) * 64;
    const int wn = (wave & 3) * 32;
    const int srow = tid >> 2, sseg = tid & 3;                     // 128 rows x 4 segs
    const int swel = (sseg ^ ((srow + (srow >> 2)) & 3)) * 8;

    f32x4 acc[4][2] = {};

    const bf16* aRow = A + (size_t)(m0 + srow) * K + swel;
    const bf16* bRow = B + (size_t)(n0 + srow) * K + swel;

    auto STAGE = [&](int step, int c) {
        char* lA = smem + c * ABYTES + tid * 16;
        char* lB = smem + 2 * ABYTES + c * ABYTES + tid * 16;
        const int off = step * 32;
        GLDS(aRow + off, lA);
        GLDS(bRow + off, lB);
    };

    const int xoff = (lk ^ ((lr + (lr >> 2)) & 3)) << 4;
    constexpr int NSTEP = K / 32;

    STAGE(0, 0);

    for (int ks = 0; ks < NSTEP; ++ks) {
        const int c = ks & 1;
        if (ks < NSTEP - 1) {
            STAGE(ks + 1, c ^ 1);
            asm volatile("s_waitcnt vmcnt(2)" ::: "memory");
        } else {
            asm volatile("s_waitcnt vmcnt(0)" ::: "memory");
        }
        __builtin_amdgcn_s_barrier();
        __builtin_amdgcn_sched_barrier(0);
        const char* aBase = smem + c * ABYTES;
        const char* bBase = smem + 2 * ABYTES + c * ABYTES;

        bf16x8 af[4], bfr[2];
#pragma unroll
        for (int i = 0; i < 4; ++i)
            af[i] = *(const bf16x8*)(aBase + (wm + i * 16 + lr) * 64 + xoff);
#pragma unroll
        for (int j = 0; j < 2; ++j)
            bfr[j] = *(const bf16x8*)(bBase + (wn + j * 16 + lr) * 64 + xoff);
#pragma unroll
        for (int i = 0; i < 4; ++i)
#pragma unroll
            for (int j = 0; j < 2; ++j)
                acc[i][j] = __builtin_amdgcn_mfma_f32_16x16x32_bf16(af[i], bfr[j], acc[i][j], 0, 0, 0);
        __builtin_amdgcn_sched_barrier(0);
        __builtin_amdgcn_s_barrier();
    }

    const int matn = n0 >> 10;   // 0=Q 1=K 2=V, uniform per block
    if (matn == 2) {
        // V: transpose 128x128 tile via LDS (stride 136), coalesced stores.
        bf16* Tl = (bf16*)smem;
        __syncthreads();
#pragma unroll
        for (int i = 0; i < 4; ++i)
#pragma unroll
            for (int j = 0; j < 2; ++j)
#pragma unroll
                for (int r = 0; r < 4; ++r) {
                    const int trow = wm + i * 16 + lk * 4 + r;   // s-local
                    const int tcol = wn + j * 16 + lr;           // col-local
                    Tl[tcol * 136 + trow] = __float2bfloat16(acc[i][j][r]);
                }
        __syncthreads();
        const int b = m0 >> 11;
        const int s0 = m0 & 2047;
#pragma unroll
        for (int k = 0; k < 4; ++k) {
            const int cc = wave * 16 + k * 4 + lk;               // tile col
            const int e = (n0 + cc) & 1023;
            const size_t bhi = (size_t)(b * 16 + (e >> 6));
            bf16* dst = vtb + (bhi * 64 + (e & 63)) * 2048 + s0 + lr * 8;
            *(uint4*)dst = *(const uint4*)&Tl[cc * 136 + lr * 8];
        }
    } else {
#pragma unroll
        for (int i = 0; i < 4; ++i)
#pragma unroll
            for (int j = 0; j < 2; ++j)
#pragma unroll
                for (int r = 0; r < 4; ++r) {
                    const int row = m0 + wm + i * 16 + lk * 4 + r;
                    const int col = n0 + wn + j * 16 + lr;
                    float v = acc[i][j][r];
                    float p = __shfl_xor(v, 1);        // RoPE pair partner
                    const int e = col & 1023;
                    const int h = e >> 6;
                    const int dd = e & 63;
                    const int b = row >> 11;
                    const int s = row & 2047;
                    const size_t bhi = (size_t)(b * 16 + h);
                    const float cs = cst[s * 32 + (dd >> 1)];
                    const float sn = snt[s * 32 + (dd >> 1)];
                    const float rv = (dd & 1) ? (p * sn + v * cs) : (v * cs - p * sn);
                    if (matn == 0)
                        qb[(bhi * 2048 + s) * 64 + dd] = __float2bfloat16(rv * SCALE_Q);
                    else
                        kb[(bhi * 2048 + s) * 64 + dd] = __float2bfloat16(rv);
                }
    }
}

// ---------------- output GEMM: 64x128 tile, BK=64 (R20 proven) ----------------
__global__ __launch_bounds__(256) void gemm_out64(
    const bf16* __restrict__ A, const bf16* __restrict__ B,
    float* __restrict__ outf)
{
    constexpr int K = 1024, N = 1024;
    constexpr int ABYTES = 64 * 128;         // 8 KB
    constexpr int BBYTES = 128 * 128;        // 16 KB
    __shared__ __align__(16) char smem[2 * (ABYTES + BBYTES)];   // 48 KB
    const int tid = threadIdx.x;
    const int wave = tid >> 6, lane = tid & 63;
    const int lr = lane & 15, lk = lane >> 4;

    // bijective XCD swizzle (nwg = 512, %8 == 0)
    const int nwg = gridDim.x * gridDim.y;
    const int flat = blockIdx.y * gridDim.x + blockIdx.x;
    const int wg = (flat & 7) * (nwg >> 3) + (flat >> 3);
    const int m0 = (wg % gridDim.x) * 64;
    const int n0 = (wg / gridDim.x) * 128;

    const int wm = (wave >> 1) * 32;
    const int wn = (wave & 1) * 64;
    const int srow = tid >> 3, sseg = tid & 7;                 // 32 rows x 8 segs / GLDS
    const int swel = (sseg ^ (srow & 7)) * 8;                  // pre-swizzled elems

    f32x4 acc[2][4] = {};

    const bf16* aRow = A + (size_t)(m0 + srow) * K + swel;
    const bf16* bRow = B + (size_t)(n0 + srow) * K + swel;
    const size_t rowK32 = (size_t)32 * K;

    auto STAGE = [&](int step, int c) {
        char* lA = smem + c * ABYTES + tid * 16;
        char* lB = smem + 2 * ABYTES + c * BBYTES + tid * 16;
        const int off = step * 64;
#pragma unroll
        for (int g = 0; g < 2; ++g)
            GLDS(aRow + off + (size_t)g * rowK32, lA + g * 4096);
#pragma unroll
        for (int g = 0; g < 4; ++g)
            GLDS(bRow + off + (size_t)g * rowK32, lB + g * 4096);
    };

    constexpr int NSTEP = K / 64;

    STAGE(0, 0);

    for (int ks = 0; ks < NSTEP; ++ks) {
        const int c = ks & 1;
        if (ks < NSTEP - 1) {
            STAGE(ks + 1, c ^ 1);
            asm volatile("s_waitcnt vmcnt(6)" ::: "memory");
        } else {
            asm volatile("s_waitcnt vmcnt(0)" ::: "memory");
        }
        __builtin_amdgcn_s_barrier();
        __builtin_amdgcn_sched_barrier(0);
        const char* aBase = smem + c * ABYTES;
        const char* bBase = smem + 2 * ABYTES + c * BBYTES;

#pragma unroll
        for (int kk = 0; kk < 2; ++kk) {
            const int seg = kk * 4 + lk;          // 16B segment 0..7
            bf16x8 af[2], bfr[4];
#pragma unroll
            for (int i = 0; i < 2; ++i) {
                const int R = wm + i * 16 + lr;
                af[i] = *(const bf16x8*)(aBase + R * 128 + ((seg ^ (R & 7)) << 4));
            }
#pragma unroll
            for (int j = 0; j < 4; ++j) {
                const int R = wn + j * 16 + lr;
                bfr[j] = *(const bf16x8*)(bBase + R * 128 + ((seg ^ (R & 7)) << 4));
            }
#pragma unroll
            for (int i = 0; i < 2; ++i)
#pragma unroll
                for (int j = 0; j < 4; ++j)
                    acc[i][j] = __builtin_amdgcn_mfma_f32_16x16x32_bf16(af[i], bfr[j], acc[i][j], 0, 0, 0);
        }
        __builtin_amdgcn_sched_barrier(0);
        __builtin_amdgcn_s_barrier();
    }

#pragma unroll
    for (int i = 0; i < 2; ++i)
#pragma unroll
        for (int j = 0; j < 4; ++j)
#pragma unroll
            for (int r = 0; r < 4; ++r) {
                const int row = m0 + wm + i * 16 + lk * 4 + r;
                const int col = n0 + wn + j * 16 + lr;
                outf[(size_t)row * N + col] = acc[i][j][r];
            }
}

// ---------------- causal flash attention (R12/R14 structure, proven 60.7us) ----------------
__global__ __launch_bounds__(256) void attn_kernel(
    const bf16* __restrict__ qb, const bf16* __restrict__ kb,
    const bf16* __restrict__ vtb, bf16* __restrict__ attnb)
{
    __shared__ __align__(16) bf16 Kl[2][64 * 64];
    __shared__ __align__(16) bf16 Vl[2][64 * 64];
    __shared__ __align__(16) bf16 Pl[4][2][16][72];   // [wave][strip][q][k], 144B rows
    const int tid = threadIdx.x;
    const int wave = tid >> 6, lane = tid & 63;
    const int lr = lane & 15, lk = lane >> 4;
    const int tA = blockIdx.x;            // 0..15  (short strip)
    const int tB = 31 - tA;               // 16..31 (long strip)
    const int bh = blockIdx.y;
    const int qA = tA * 64 + wave * 16;
    const int qB = tB * 64 + wave * 16;

    const bf16* Qp = qb + (size_t)bh * 2048 * 64;
    const bf16* Kp = kb + (size_t)bh * 2048 * 64;
    const bf16* Vp = vtb + (size_t)bh * 64 * 2048;

    const int srow = tid >> 3;
    const int sseg = tid & 7;
    const int sw16 = (sseg ^ (srow & 7)) * 16;
    const char* kg = (const char*)Kp + (size_t)srow * 128 + sw16;
    const char* vg = (const char*)Vp + (size_t)srow * 4096 + sw16;

#define STAGE(kt_, c_) do {                                              \
        const char* kgt = kg + (size_t)(kt_) * 8192;                     \
        GLDS(kgt,              &Kl[c_][0] + tid * 8);                    \
        GLDS(kgt + 32 * 128,   &Kl[c_][0] + 2048 + tid * 8);             \
        const char* vgt = vg + (size_t)(kt_) * 128;                      \
        GLDS(vgt,              &Vl[c_][0] + tid * 8);                    \
        GLDS(vgt + 32 * 4096,  &Vl[c_][0] + 2048 + tid * 8);             \
    } while (0)

    bf16x8 qfA[2], qfB[2];
#pragma unroll
    for (int ks = 0; ks < 2; ++ks) {
        qfA[ks] = *(const bf16x8*)(Qp + (qA + lr) * 64 + ks * 32 + lk * 8);
        qfB[ks] = *(const bf16x8*)(Qp + (qB + lr) * 64 + ks * 32 + lk * 8);
    }

    float sA = 0.f, sB = 0.f;
    f32x4 oA[4] = {}, oB[4] = {};

    STAGE(0, 0);

    const int xoff = (lr & 7) * 8;   // K/V swizzle: row&7 == lr&7 for rows j*16+lr

    for (int kt = 0; kt <= tB; ++kt) {
        const int c = kt & 1;
        const int kv0 = kt * 64;
        const bool doA = (kt <= tA);
        if (kt < tB) {
            STAGE(kt + 1, c ^ 1);
            asm volatile("s_waitcnt vmcnt(4)" ::: "memory");  // kt landed; kt+1 in flight
        } else {
            asm volatile("s_waitcnt vmcnt(0)" ::: "memory");
        }
        __builtin_amdgcn_s_barrier();
        __builtin_amdgcn_sched_barrier(0);
        const bf16* Kc = &Kl[c][0];
        const bf16* Vc = &Vl[c][0];

        // ---- QK^T (swapped): scX[j][r] = P^T[k = j*16+lk*4+r][q = lr] ----
        f32x4 scB[4] = {}, scA[4] = {};
#pragma unroll
        for (int ks = 0; ks < 2; ++ks) {
            bf16x8 kf[4];
#pragma unroll
            for (int j = 0; j < 4; ++j)
                kf[j] = *(const bf16x8*)(Kc + (j * 16 + lr) * 64 + ((ks * 32 + lk * 8) ^ xoff));
            __builtin_amdgcn_s_setprio(1);
#pragma unroll
            for (int j = 0; j < 4; ++j)
                scB[j] = __builtin_amdgcn_mfma_f32_16x16x32_bf16(kf[j], qfB[ks], scB[j], 0, 0, 0);
            if (doA) {
#pragma unroll
                for (int j = 0; j < 4; ++j)
                    scA[j] = __builtin_amdgcn_mfma_f32_16x16x32_bf16(kf[j], qfA[ks], scA[j], 0, 0, 0);
            }
            __builtin_amdgcn_s_setprio(0);
        }

        // vf hoisted once per visit; loads overlap the softmax below
        bf16x8 vf[2][4];
#pragma unroll
        for (int ks = 0; ks < 2; ++ks)
#pragma unroll
            for (int j = 0; j < 4; ++j)
                vf[ks][j] = *(const bf16x8*)(Vc + (j * 16 + lr) * 64 + ((ks * 32 + lk * 8) ^ xoff));

        // ---- fixed-max softmax: P = exp2(sc - MFIX); branchless, lane-local ----
        auto smx = [&](f32x4* sc, float& ssum, int qX, bool diag, int st) {
            if (diag) {
#pragma unroll
                for (int j = 0; j < 4; ++j)
#pragma unroll
                    for (int r = 0; r < 4; ++r)
                        if (kv0 + j * 16 + lk * 4 + r > qX + lr) sc[j][r] = -1e30f;
            }
            float l0 = 0.f, l1 = 0.f, l2 = 0.f, l3 = 0.f;
#pragma unroll
            for (int j = 0; j < 4; ++j) {
                float pv[4];
                pv[0] = exp2f(sc[j][0] - MFIX);
                pv[1] = exp2f(sc[j][1] - MFIX);
                pv[2] = exp2f(sc[j][2] - MFIX);
                pv[3] = exp2f(sc[j][3] - MFIX);
                l0 += pv[0]; l1 += pv[1]; l2 += pv[2]; l3 += pv[3];
                union { bf16 h[4]; ushort4 s4; } u;
#pragma unroll
                for (int r = 0; r < 4; ++r) u.h[r] = __float2bfloat16(pv[r]);
                *(ushort4*)(&Pl[wave][st][lr][j * 16 + lk * 4]) = u.s4;
            }
            ssum += (l0 + l1) + (l2 + l3);
        };
        // ---- PV for strip st: o[j] (= O^T[d][q]) += mfma(vf, pf) ----
        auto pv = [&](f32x4* o, int st) {
#pragma unroll
            for (int ks = 0; ks < 2; ++ks) {
                const bf16x8 pf = *(const bf16x8*)(&Pl[wave][st][lr][ks * 32 + lk * 8]);
                __builtin_amdgcn_s_setprio(1);
#pragma unroll
                for (int j = 0; j < 4; ++j)
                    o[j] = __builtin_amdgcn_mfma_f32_16x16x32_bf16(vf[ks][j], pf, o[j], 0, 0, 0);
                __builtin_amdgcn_s_setprio(0);
            }
        };

        smx(scB, sB, qB, kt == tB, 1);
        if (doA) smx(scA, sA, qA, kt == tA, 0);
        pv(oB, 1);
        if (doA) pv(oA, 0);

        __builtin_amdgcn_sched_barrier(0);
        __builtin_amdgcn_s_barrier();   // all reads of buf c done before next stage overwrites
    }

    const int b = bh >> 4, h = bh & 15;
    auto epi = [&](float ssum, f32x4* o, int qX) {
        float s = ssum;
        s += __shfl_xor(s, 16);
        s += __shfl_xor(s, 32);
        const float inv = 1.0f / s;
        const int qq = qX + lr;
        bf16* dst = attnb + (size_t)(b * 2048 + qq) * 1024 + h * 64 + lk * 4;
#pragma unroll
        for (int j = 0; j < 4; ++j) {
            union { bf16 h4[4]; ushort4 s4; } u;
#pragma unroll
            for (int r = 0; r < 4; ++r) u.h4[r] = __float2bfloat16(o[j][r] * inv);
            *(ushort4*)(dst + j * 16) = u.s4;
        }
    };
    epi(sA, oA, qA);
    epi(sB, oB, qB);
#undef STAGE
}

// ---------------- launch ----------------
extern "C" void kernel_launch(void* const* d_in, const int* in_sizes, int n_in,
                              void* d_out, int out_size, void* d_ws, size_t ws_size,
                              hipStream_t stream)
{
    const float* x   = (const float*)d_in[0];
    const float* wq  = (const float*)d_in[1];
    const float* wk  = (const float*)d_in[2];
    const float* wv  = (const float*)d_in[3];
    const float* wo  = (const float*)d_in[4];
    const int*   pos = (const int*)d_in[5];
    const void* theta = d_in[6];

    char* ws = (char*)d_ws;
    bf16* xb    = (bf16*)(ws + OFF_XB);
    bf16* attnb = (bf16*)(ws + OFF_XB);    // reuse: xb consumed before attn writes
    bf16* wqkvb = (bf16*)(ws + OFF_WQKVB);
    bf16* wob   = (bf16*)(ws + OFF_WOB);
    bf16* qb    = (bf16*)(ws + OFF_QB);
    bf16* kb    = (bf16*)(ws + OFF_KB);
    bf16* vtb   = (bf16*)(ws + OFF_VTB);
    float* cst  = (float*)(ws + OFF_CS);
    float* snt  = (float*)(ws + OFF_SN);

    prep_kernel<<<8448, 256, 0, stream>>>(x, wq, wk, wv, wo, xb, wqkvb, wob,
                                          pos, theta, cst, snt);
    gemm_qkv512<<<dim3(32, 24), 512, 0, stream>>>(xb, wqkvb, qb, kb, vtb, cst, snt);
    attn_kernel<<<dim3(16, 32), 256, 0, stream>>>(qb, kb, vtb, attnb);
    gemm_out64<<<dim3(64, 8), 256, 0, stream>>>(attnb, wob, (float*)d_out);
}